// Round 15
// baseline (58.435 us; speedup 1.0000x reference)
//
#include <hip/hip_runtime.h>
#include <math.h>

#define B_ 32
#define N_ 2048
#define D_ 512
#define K_ 128
#define GAMMA_ 10.0f
#define EPS_ 1e-12f
#define STEPS_ 10
#define SHIFT_ 18.0f
#define EXP_NEG_SHIFT_ 1.5229979e-08f  // exp(-18)

typedef _Float16 f16x8 __attribute__((ext_vector_type(8)));
typedef _Float16 f16x4 __attribute__((ext_vector_type(4)));
typedef float f32x16 __attribute__((ext_vector_type(16)));

// ---------------- k1: quantize t to f16 in MFMA-fragment-contiguous layout ----------------
// unit u (16B = 8 f16) = (c*8 + s)*128 + k   where c = d>>6, s = (d&63)>>3
__global__ void k_prep_t(const float* __restrict__ ts, _Float16* __restrict__ tq,
                         float* __restrict__ rt, float* __restrict__ tnn) {
    int k = blockIdx.x;      // 128
    int lane = threadIdx.x;  // 64
    const float4* rp = (const float4*)(ts + (size_t)k * D_ + lane * 8);
    float4 v0 = rp[0], v1 = rp[1];
    f16x8 hv;
    hv[0] = (_Float16)v0.x; hv[1] = (_Float16)v0.y; hv[2] = (_Float16)v0.z; hv[3] = (_Float16)v0.w;
    hv[4] = (_Float16)v1.x; hv[5] = (_Float16)v1.y; hv[6] = (_Float16)v1.z; hv[7] = (_Float16)v1.w;
    float ssq = 0.f;
#pragma unroll
    for (int j = 0; j < 8; ++j) { float x = (float)hv[j]; ssq += x * x; }
#pragma unroll
    for (int off = 32; off; off >>= 1) ssq += __shfl_xor(ssq, off);
    if (lane == 0) {
        float rtv = (float)(1.0 / sqrt((double)ssq + 1e-12));
        rt[k] = rtv;
        tnn[k] = ssq * rtv * rtv;
    }
    *(f16x8*)&tq[((size_t)lane * 128 + k) * 8] = hv;
}

// ---------------- k2: MFMA GEMM + exp epilogue + fused column sums (R13 anchor, frozen) ----------------
// tile: 128 k x 32 n, D chunked by 64, grid = B * 64 n-tiles = 2048 blocks
__global__ __launch_bounds__(256, 6) void k_gemm(
    const float* __restrict__ features,  // [B][N][D] f32
    const _Float16* __restrict__ tq,     // frag-contiguous f16
    const float* __restrict__ rt, const float* __restrict__ tnn,
    _Float16* __restrict__ E,            // [B][K][N] f16, SHIFTED by exp(+18)
    float* __restrict__ A1)              // [B][N], shifted colsums
{
    __shared__ _Float16 Bf[2][32 * 64];  // 8 KB double-buffered f tile
    __shared__ float rowssq[32];
    __shared__ float csum[4][32];
    __shared__ float ldsrt[128], ldstnn[128];

    const int tid = threadIdx.x;
    const int b = blockIdx.x >> 6;
    const int n0 = (blockIdx.x & 63) * 32;
    const int w = tid >> 6;       // wave id: k rows [w*32, w*32+32)
    const int l = tid & 63;
    const int hi = l >> 5;
    const int l31 = l & 31;

    if (tid < 128) { ldsrt[tid] = rt[tid]; ldstnn[tid] = tnn[tid]; }

    const int fq = tid & 7;       // float4 sub-position within row chunk
    const int r0 = tid >> 3;      // 0..31 : feature row staged by this thread
    const float4* fbase = (const float4*)(features + ((size_t)(b * N_ + n0)) * D_);

    float ss = 0.f;               // f16-rounded partial sumsq of feature row r0
    f32x16 acc;
#pragma unroll
    for (int i = 0; i < 16; ++i) acc[i] = 0.f;

    float4 br[2];
    f16x8 apre[4];                // register-prefetched A fragments for current chunk

    auto stage_load = [&](int c) {
#pragma unroll
        for (int i = 0; i < 2; ++i)
            br[i] = fbase[(size_t)r0 * 128 + c * 16 + fq + i * 8];
    };

    auto a_load = [&](int c) {
#pragma unroll
        for (int ks = 0; ks < 4; ++ks) {
            int sB = ks * 2 + hi;
            size_t u = (size_t)(c * 8 + sB) * 128 + w * 32 + l31;
            apre[ks] = *(const f16x8*)&tq[u * 8];
        }
    };

    auto stage_write = [&](int buf) {
#pragma unroll
        for (int i = 0; i < 2; ++i) {
            float4 v = br[i];
            f16x4 hv;
            hv[0] = (_Float16)v.x; hv[1] = (_Float16)v.y;
            hv[2] = (_Float16)v.z; hv[3] = (_Float16)v.w;
            float q0 = (float)hv[0], q1 = (float)hv[1], q2 = (float)hv[2], q3 = (float)hv[3];
            ss += q0 * q0 + q1 * q1 + q2 * q2 + q3 * q3;
            int q = fq + i * 8;          // float4 index within 64-d chunk (0..15)
            int s = q >> 1;              // 16B slot 0..7
            int hh = q & 1;              // half within slot
            int idx = r0 * 64 + ((s ^ (r0 & 7)) << 3) + hh * 4;  // f16 units
            *(f16x4*)&Bf[buf][idx] = hv;
        }
    };

    auto compute = [&](int cur) {
#pragma unroll
        for (int ks = 0; ks < 4; ++ks) {
            int sB = ks * 2 + hi;
            f16x8 bfr = *(const f16x8*)&Bf[cur][l31 * 64 + ((sB ^ (l31 & 7)) << 3)];
            acc = __builtin_amdgcn_mfma_f32_32x32x16_f16(apre[ks], bfr, acc, 0, 0, 0);
        }
    };

    stage_load(0);
    a_load(0);
    stage_write(0);
    __syncthreads();

#pragma unroll
    for (int c = 0; c < 8; ++c) {
        int cur = c & 1;
        if (c < 7) stage_load(c + 1);   // issue next feature loads early (T14)
        compute(cur);                    // consumes apre (chunk c) + Bf[cur]
        if (c < 7) a_load(c + 1);        // refill A prefetch
        if (c < 7) stage_write(cur ^ 1);
        __syncthreads();
    }

    // ---- epilogue ----
    ss += __shfl_xor(ss, 1);
    ss += __shfl_xor(ss, 2);
    ss += __shfl_xor(ss, 4);
    if (fq == 0) rowssq[r0] = ss;
    __syncthreads();

    const int n = n0 + l31;
    float rsq = rowssq[l31];
    float rf = (float)(1.0 / sqrt((double)rsq + 1e-12));
    float fnn = rsq * rf * rf;
    float cs = 0.f;
#pragma unroll
    for (int r = 0; r < 16; ++r) {
        int krow = (r & 3) + 8 * (r >> 2) + 4 * hi;
        int k = w * 32 + krow;
        float cb = ldstnn[k] + fnn - 2.0f * ldsrt[k] * rf * acc[r];
        float e = expf(SHIFT_ - GAMMA_ * cb);   // shifted into f16 normal range
        _Float16 eh = (_Float16)e;
        cs += (float)eh;                        // sum exactly what we store
        E[((size_t)(b * K_ + k)) * N_ + n] = eh;
    }
    cs += __shfl_xor(cs, 32);                   // merge hi-half's k rows
    if (!hi) csum[w][l31] = cs;
    __syncthreads();
    if (tid < 32)
        A1[b * N_ + n0 + tid] = csum[0][tid] + csum[1][tid] + csum[2][tid] + csum[3][tid];
}

// ---------------- k4: collapsed Sinkhorn loop, vectorized n = tid*8 + r mapping ----------------
__global__ __launch_bounds__(256) void k_sinkhorn(const float* __restrict__ tr,
                                                  const float* __restrict__ c_u,
                                                  const float* __restrict__ A1,
                                                  float* __restrict__ out,
                                                  float* __restrict__ wfb) {
    __shared__ float sc0[4], sc1[4], sres[2];
    int b = blockIdx.x, tid = threadIdx.x;
    float mu = tr[b];
    const float nf = (float)N_;
    float a0[8], a1[8], w[8];
    {
        const float4* cu4 = (const float4*)&c_u[b * N_ + tid * 8];
        const float4* a14 = (const float4*)&A1[b * N_ + tid * 8];
        float4 c0 = cu4[0], c1 = cu4[1];
        float4 v0 = a14[0], v1 = a14[1];
        a0[0] = expf(-GAMMA_ * c0.x); a0[1] = expf(-GAMMA_ * c0.y);
        a0[2] = expf(-GAMMA_ * c0.z); a0[3] = expf(-GAMMA_ * c0.w);
        a0[4] = expf(-GAMMA_ * c1.x); a0[5] = expf(-GAMMA_ * c1.y);
        a0[6] = expf(-GAMMA_ * c1.z); a0[7] = expf(-GAMMA_ * c1.w);
        a1[0] = v0.x * EXP_NEG_SHIFT_; a1[1] = v0.y * EXP_NEG_SHIFT_;
        a1[2] = v0.z * EXP_NEG_SHIFT_; a1[3] = v0.w * EXP_NEG_SHIFT_;
        a1[4] = v1.x * EXP_NEG_SHIFT_; a1[5] = v1.y * EXP_NEG_SHIFT_;
        a1[6] = v1.z * EXP_NEG_SHIFT_; a1[7] = v1.w * EXP_NEG_SHIFT_;
#pragma unroll
        for (int r = 0; r < 8; ++r) w[r] = 1.f;
    }
    float alpha = 1.f, beta = 1.f;
    for (int s = 0; s < STEPS_; ++s) {
        float p0 = 0.f, p1 = 0.f;
#pragma unroll
        for (int r = 0; r < 8; ++r) {
            float cs = w[r] * (alpha * a0[r] + beta * a1[r]);
            w[r] = w[r] / (cs * nf + EPS_);
            p0 += a0[r] * w[r];
            p1 += a1[r] * w[r];
        }
#pragma unroll
        for (int off = 32; off; off >>= 1) {
            p0 += __shfl_xor(p0, off);
            p1 += __shfl_xor(p1, off);
        }
        int wid = tid >> 6;
        if ((tid & 63) == 0) { sc0[wid] = p0; sc1[wid] = p1; }
        __syncthreads();
        if (tid == 0) {
            sres[0] = sc0[0] + sc0[1] + sc0[2] + sc0[3];
            sres[1] = sc1[0] + sc1[1] + sc1[2] + sc1[3];
        }
        __syncthreads();
        float s0 = alpha * sres[0], ssum = beta * sres[1];
        alpha *= (1.f - mu) / (s0 + EPS_);
        beta *= mu / (ssum + EPS_);
    }
    {
        float ov[8], wv[8];
#pragma unroll
        for (int r = 0; r < 8; ++r) {
            float cs = w[r] * (alpha * a0[r] + beta * a1[r]);
            float wf = w[r] / (cs * nf + EPS_);
            ov[r] = alpha * a0[r] * wf;                 // row 0 of P
            wv[r] = beta * wf * EXP_NEG_SHIFT_;         // scale for rows 1..K
        }
        float4* o4 = (float4*)&out[(size_t)b * (K_ + 1) * N_ + tid * 8];
        float4* w4 = (float4*)&wfb[b * N_ + tid * 8];
        o4[0] = make_float4(ov[0], ov[1], ov[2], ov[3]);
        o4[1] = make_float4(ov[4], ov[5], ov[6], ov[7]);
        w4[0] = make_float4(wv[0], wv[1], wv[2], wv[3]);
        w4[1] = make_float4(wv[4], wv[5], wv[6], wv[7]);
    }
}

// ---------------- k5: P rows 1..K = E * wfb  (16 elems/thread, plain stores) ----------------
__global__ void k_scale(const _Float16* __restrict__ E, const float* __restrict__ wfb,
                        float* __restrict__ out) {
    size_t g = (size_t)blockIdx.x * 256 + threadIdx.x;
    size_t idx = g * 16;
    int b = (int)(idx >> 18);            // / (K*N) = 2^18
    int rem = (int)(idx & ((K_ * N_) - 1));
    int k = rem >> 11, n = rem & (N_ - 1);
    f16x8 e0 = *(const f16x8*)&E[idx];
    f16x8 e1 = *(const f16x8*)&E[idx + 8];
    const float4* wp = (const float4*)&wfb[b * N_ + n];
    float4* op = (float4*)&out[((size_t)(b * (K_ + 1) + 1 + k)) * N_ + n];
    float4 wq0 = wp[0], wq1 = wp[1], wq2 = wp[2], wq3 = wp[3];
    float4 o0, o1, o2, o3;
    o0.x = (float)e0[0] * wq0.x; o0.y = (float)e0[1] * wq0.y;
    o0.z = (float)e0[2] * wq0.z; o0.w = (float)e0[3] * wq0.w;
    o1.x = (float)e0[4] * wq1.x; o1.y = (float)e0[5] * wq1.y;
    o1.z = (float)e0[6] * wq1.z; o1.w = (float)e0[7] * wq1.w;
    o2.x = (float)e1[0] * wq2.x; o2.y = (float)e1[1] * wq2.y;
    o2.z = (float)e1[2] * wq2.z; o2.w = (float)e1[3] * wq2.w;
    o3.x = (float)e1[4] * wq3.x; o3.y = (float)e1[5] * wq3.y;
    o3.z = (float)e1[6] * wq3.z; o3.w = (float)e1[7] * wq3.w;
    op[0] = o0; op[1] = o1; op[2] = o2; op[3] = o3;
}

extern "C" void kernel_launch(void* const* d_in, const int* in_sizes, int n_in,
                              void* d_out, int out_size, void* d_ws, size_t ws_size,
                              hipStream_t stream) {
    const float* features = (const float*)d_in[0];
    const float* tr = (const float*)d_in[1];
    const float* c_u = (const float*)d_in[2];
    const float* ts = (const float*)d_in[3];
    float* out = (float*)d_out;

    char* ws = (char*)d_ws;
    _Float16* tq = (_Float16*)ws;                 // 128*512 f16 = 128 KiB
    float* rt = (float*)(ws + 131072);            // 512 B
    float* tnn = (float*)(ws + 131584);           // 512 B
    float* A1 = (float*)(ws + 132096);            // B*N f32 = 256 KiB
    float* wfb = (float*)(ws + 132096 + 262144);  // 256 KiB
    _Float16* E = (_Float16*)(ws + 132096 + 524288);  // B*K*N f16 = 16 MiB
    (void)in_sizes; (void)n_in; (void)out_size; (void)ws_size;

    k_prep_t<<<K_, 64, 0, stream>>>(ts, tq, rt, tnn);
    k_gemm<<<B_ * 64, 256, 0, stream>>>(features, tq, rt, tnn, E, A1);
    k_sinkhorn<<<B_, 256, 0, stream>>>(tr, c_u, A1, out, wfb);
    k_scale<<<(B_ * K_ * N_) / (16 * 256), 256, 0, stream>>>(E, wfb, out);
}

// Round 16
// 54.755 us; speedup vs baseline: 1.0672x; 1.0672x over previous
//
#include <hip/hip_runtime.h>
#include <math.h>

#define B_ 32
#define N_ 2048
#define D_ 512
#define K_ 128
#define GAMMA_ 10.0f
#define EPS_ 1e-12f
#define STEPS_ 10
#define SHIFT_ 18.0f
#define EXP_NEG_SHIFT_ 1.5229979e-08f  // exp(-18)

typedef _Float16 f16x8 __attribute__((ext_vector_type(8)));
typedef _Float16 f16x4 __attribute__((ext_vector_type(4)));
typedef float f32x16 __attribute__((ext_vector_type(16)));

// ---------------- k1: quantize t to f16 in MFMA-fragment-contiguous layout ----------------
// unit u (16B = 8 f16) = (c*8 + s)*128 + k   where c = d>>6, s = (d&63)>>3
__global__ void k_prep_t(const float* __restrict__ ts, _Float16* __restrict__ tq,
                         float* __restrict__ rt, float* __restrict__ tnn) {
    int k = blockIdx.x;      // 128
    int lane = threadIdx.x;  // 64
    const float4* rp = (const float4*)(ts + (size_t)k * D_ + lane * 8);
    float4 v0 = rp[0], v1 = rp[1];
    f16x8 hv;
    hv[0] = (_Float16)v0.x; hv[1] = (_Float16)v0.y; hv[2] = (_Float16)v0.z; hv[3] = (_Float16)v0.w;
    hv[4] = (_Float16)v1.x; hv[5] = (_Float16)v1.y; hv[6] = (_Float16)v1.z; hv[7] = (_Float16)v1.w;
    float ssq = 0.f;
#pragma unroll
    for (int j = 0; j < 8; ++j) { float x = (float)hv[j]; ssq += x * x; }
#pragma unroll
    for (int off = 32; off; off >>= 1) ssq += __shfl_xor(ssq, off);
    if (lane == 0) {
        float rtv = (float)(1.0 / sqrt((double)ssq + 1e-12));
        rt[k] = rtv;
        tnn[k] = ssq * rtv * rtv;
    }
    *(f16x8*)&tq[((size_t)lane * 128 + k) * 8] = hv;
}

// ---------------- k2: MFMA GEMM + exp epilogue + fused column sums ----------------
// tile: 128 k x 32 n, D chunked by 64, grid = B * 64 n-tiles = 2048 blocks
// wave w owns k rows [w*32, w*32+32); A (t) fragments register-prefetched from global (L2)
__global__ __launch_bounds__(256, 6) void k_gemm(
    const float* __restrict__ features,  // [B][N][D] f32
    const _Float16* __restrict__ tq,     // frag-contiguous f16
    const float* __restrict__ rt, const float* __restrict__ tnn,
    _Float16* __restrict__ E,            // [B][K][N] f16, SHIFTED by exp(+18)
    float* __restrict__ A1)              // [B][N], shifted colsums
{
    __shared__ _Float16 Bf[2][32 * 64];  // 8 KB double-buffered f tile
    __shared__ float rowssq[32];
    __shared__ float csum[4][32];
    __shared__ float ldsrt[128], ldstnn[128];

    const int tid = threadIdx.x;
    const int b = blockIdx.x >> 6;
    const int n0 = (blockIdx.x & 63) * 32;
    const int w = tid >> 6;       // wave id: k rows [w*32, w*32+32)
    const int l = tid & 63;
    const int hi = l >> 5;
    const int l31 = l & 31;

    if (tid < 128) { ldsrt[tid] = rt[tid]; ldstnn[tid] = tnn[tid]; }

    const int fq = tid & 7;       // float4 sub-position within row chunk
    const int r0 = tid >> 3;      // 0..31 : feature row staged by this thread
    const float4* fbase = (const float4*)(features + ((size_t)(b * N_ + n0)) * D_);

    float ss = 0.f;               // f16-rounded partial sumsq of feature row r0
    f32x16 acc;
#pragma unroll
    for (int i = 0; i < 16; ++i) acc[i] = 0.f;

    float4 br[2];
    f16x8 apre[4];                // register-prefetched A fragments for current chunk

    auto stage_load = [&](int c) {
#pragma unroll
        for (int i = 0; i < 2; ++i)
            br[i] = fbase[(size_t)r0 * 128 + c * 16 + fq + i * 8];
    };

    auto a_load = [&](int c) {
#pragma unroll
        for (int ks = 0; ks < 4; ++ks) {
            int sB = ks * 2 + hi;
            size_t u = (size_t)(c * 8 + sB) * 128 + w * 32 + l31;
            apre[ks] = *(const f16x8*)&tq[u * 8];
        }
    };

    auto stage_write = [&](int buf) {
#pragma unroll
        for (int i = 0; i < 2; ++i) {
            float4 v = br[i];
            f16x4 hv;
            hv[0] = (_Float16)v.x; hv[1] = (_Float16)v.y;
            hv[2] = (_Float16)v.z; hv[3] = (_Float16)v.w;
            float q0 = (float)hv[0], q1 = (float)hv[1], q2 = (float)hv[2], q3 = (float)hv[3];
            ss += q0 * q0 + q1 * q1 + q2 * q2 + q3 * q3;
            int q = fq + i * 8;          // float4 index within 64-d chunk (0..15)
            int s = q >> 1;              // 16B slot 0..7
            int hh = q & 1;              // half within slot
            int idx = r0 * 64 + ((s ^ (r0 & 7)) << 3) + hh * 4;  // f16 units
            *(f16x4*)&Bf[buf][idx] = hv;
        }
    };

    auto compute = [&](int cur) {
#pragma unroll
        for (int ks = 0; ks < 4; ++ks) {
            int sB = ks * 2 + hi;
            f16x8 bfr = *(const f16x8*)&Bf[cur][l31 * 64 + ((sB ^ (l31 & 7)) << 3)];
            acc = __builtin_amdgcn_mfma_f32_32x32x16_f16(apre[ks], bfr, acc, 0, 0, 0);
        }
    };

    stage_load(0);
    a_load(0);
    stage_write(0);
    __syncthreads();

#pragma unroll
    for (int c = 0; c < 8; ++c) {
        int cur = c & 1;
        if (c < 7) stage_load(c + 1);   // issue next feature loads early (T14)
        compute(cur);                    // consumes apre (chunk c) + Bf[cur]
        if (c < 7) a_load(c + 1);        // refill A prefetch
        if (c < 7) stage_write(cur ^ 1);
        __syncthreads();
    }

    // ---- epilogue ----
    ss += __shfl_xor(ss, 1);
    ss += __shfl_xor(ss, 2);
    ss += __shfl_xor(ss, 4);
    if (fq == 0) rowssq[r0] = ss;
    __syncthreads();

    const int n = n0 + l31;
    float rsq = rowssq[l31];
    float rf = (float)(1.0 / sqrt((double)rsq + 1e-12));
    float fnn = rsq * rf * rf;
    float cs = 0.f;
#pragma unroll
    for (int r = 0; r < 16; ++r) {
        int krow = (r & 3) + 8 * (r >> 2) + 4 * hi;
        int k = w * 32 + krow;
        float cb = ldstnn[k] + fnn - 2.0f * ldsrt[k] * rf * acc[r];
        float e = expf(SHIFT_ - GAMMA_ * cb);   // shifted into f16 normal range
        _Float16 eh = (_Float16)e;
        cs += (float)eh;                        // sum exactly what we store
        E[((size_t)(b * K_ + k)) * N_ + n] = eh;
    }
    cs += __shfl_xor(cs, 32);                   // merge hi-half's k rows
    if (!hi) csum[w][l31] = cs;
    __syncthreads();
    if (tid < 32)
        A1[b * N_ + n0 + tid] = csum[0][tid] + csum[1][tid] + csum[2][tid] + csum[3][tid];
}

// ---------------- k4: collapsed Sinkhorn loop (A0 computed inline) ----------------
__global__ __launch_bounds__(256) void k_sinkhorn(const float* __restrict__ tr,
                                                  const float* __restrict__ c_u,
                                                  const float* __restrict__ A1,
                                                  float* __restrict__ out,
                                                  float* __restrict__ wfb) {
    __shared__ float sc0[4], sc1[4], sres[2];
    int b = blockIdx.x, tid = threadIdx.x;
    float mu = tr[b];
    const float nf = (float)N_;
    float a0[8], a1[8], w[8];
#pragma unroll
    for (int r = 0; r < 8; ++r) {
        int n = tid + 256 * r;
        a0[r] = expf(-GAMMA_ * c_u[b * N_ + n]);
        a1[r] = A1[b * N_ + n] * EXP_NEG_SHIFT_;   // undo global shift exactly in f32
        w[r] = 1.f;
    }
    float alpha = 1.f, beta = 1.f;
    for (int s = 0; s < STEPS_; ++s) {
        float p0 = 0.f, p1 = 0.f;
#pragma unroll
        for (int r = 0; r < 8; ++r) {
            float cs = w[r] * (alpha * a0[r] + beta * a1[r]);
            w[r] = w[r] / (cs * nf + EPS_);
            p0 += a0[r] * w[r];
            p1 += a1[r] * w[r];
        }
#pragma unroll
        for (int off = 32; off; off >>= 1) {
            p0 += __shfl_xor(p0, off);
            p1 += __shfl_xor(p1, off);
        }
        int wid = tid >> 6;
        if ((tid & 63) == 0) { sc0[wid] = p0; sc1[wid] = p1; }
        __syncthreads();
        if (tid == 0) {
            sres[0] = sc0[0] + sc0[1] + sc0[2] + sc0[3];
            sres[1] = sc1[0] + sc1[1] + sc1[2] + sc1[3];
        }
        __syncthreads();
        float s0 = alpha * sres[0], ssum = beta * sres[1];
        alpha *= (1.f - mu) / (s0 + EPS_);
        beta *= mu / (ssum + EPS_);
    }
#pragma unroll
    for (int r = 0; r < 8; ++r) {
        int n = tid + 256 * r;
        float cs = w[r] * (alpha * a0[r] + beta * a1[r]);
        float wf = w[r] / (cs * nf + EPS_);
        out[(size_t)b * (K_ + 1) * N_ + n] = alpha * a0[r] * wf;  // row 0
        wfb[b * N_ + n] = beta * wf * EXP_NEG_SHIFT_;             // fold shift for rows 1..K
    }
}

// ---------------- k5: P rows 1..K = E * wfb ----------------
__global__ void k_scale(const _Float16* __restrict__ E, const float* __restrict__ wfb,
                        float* __restrict__ out) {
    size_t g = (size_t)blockIdx.x * 256 + threadIdx.x;
    size_t idx = g * 8;
    int b = (int)(idx >> 18);            // / (K*N) = 2^18
    int rem = (int)(idx & ((K_ * N_) - 1));
    int k = rem >> 11, n = rem & (N_ - 1);
    f16x8 e = *(const f16x8*)&E[idx];
    float4 w0 = *(const float4*)&wfb[b * N_ + n];
    float4 w1 = *(const float4*)&wfb[b * N_ + n + 4];
    float* op = &out[((size_t)(b * (K_ + 1) + 1 + k)) * N_ + n];
    float4 o0, o1;
    o0.x = (float)e[0] * w0.x; o0.y = (float)e[1] * w0.y;
    o0.z = (float)e[2] * w0.z; o0.w = (float)e[3] * w0.w;
    o1.x = (float)e[4] * w1.x; o1.y = (float)e[5] * w1.y;
    o1.z = (float)e[6] * w1.z; o1.w = (float)e[7] * w1.w;
    *(float4*)op = o0;
    *(float4*)(op + 4) = o1;
}

extern "C" void kernel_launch(void* const* d_in, const int* in_sizes, int n_in,
                              void* d_out, int out_size, void* d_ws, size_t ws_size,
                              hipStream_t stream) {
    const float* features = (const float*)d_in[0];
    const float* tr = (const float*)d_in[1];
    const float* c_u = (const float*)d_in[2];
    const float* ts = (const float*)d_in[3];
    float* out = (float*)d_out;

    char* ws = (char*)d_ws;
    _Float16* tq = (_Float16*)ws;                 // 128*512 f16 = 128 KiB
    float* rt = (float*)(ws + 131072);            // 512 B
    float* tnn = (float*)(ws + 131584);           // 512 B
    float* A1 = (float*)(ws + 132096);            // B*N f32 = 256 KiB
    float* wfb = (float*)(ws + 132096 + 262144);  // 256 KiB
    _Float16* E = (_Float16*)(ws + 132096 + 524288);  // B*K*N f16 = 16 MiB
    (void)in_sizes; (void)n_in; (void)out_size; (void)ws_size;

    k_prep_t<<<K_, 64, 0, stream>>>(ts, tq, rt, tnn);
    k_gemm<<<B_ * 64, 256, 0, stream>>>(features, tq, rt, tnn, E, A1);
    k_sinkhorn<<<B_, 256, 0, stream>>>(tr, c_u, A1, out, wfb);
    k_scale<<<(B_ * K_ * N_) / (8 * 256), 256, 0, stream>>>(E, wfb, out);
}

// Round 17
// 54.478 us; speedup vs baseline: 1.0726x; 1.0051x over previous
//
#include <hip/hip_runtime.h>
#include <math.h>

#define B_ 32
#define N_ 2048
#define D_ 512
#define K_ 128
#define GAMMA_ 10.0f
#define EPS_ 1e-12f
#define STEPS_ 10
#define SHIFT_ 18.0f
#define EXP_NEG_SHIFT_ 1.5229979e-08f  // exp(-18)

typedef _Float16 f16x8 __attribute__((ext_vector_type(8)));
typedef _Float16 f16x4 __attribute__((ext_vector_type(4)));
typedef float f32x16 __attribute__((ext_vector_type(16)));

// ---------------- k1: quantize t to f16 in MFMA-fragment-contiguous layout ----------------
// unit u (16B = 8 f16) = (c*8 + s)*128 + k   where c = d>>6, s = (d&63)>>3
__global__ void k_prep_t(const float* __restrict__ ts, _Float16* __restrict__ tq,
                         float* __restrict__ rt, float* __restrict__ tnn) {
    int k = blockIdx.x;      // 128
    int lane = threadIdx.x;  // 64
    const float4* rp = (const float4*)(ts + (size_t)k * D_ + lane * 8);
    float4 v0 = rp[0], v1 = rp[1];
    f16x8 hv;
    hv[0] = (_Float16)v0.x; hv[1] = (_Float16)v0.y; hv[2] = (_Float16)v0.z; hv[3] = (_Float16)v0.w;
    hv[4] = (_Float16)v1.x; hv[5] = (_Float16)v1.y; hv[6] = (_Float16)v1.z; hv[7] = (_Float16)v1.w;
    float ssq = 0.f;
#pragma unroll
    for (int j = 0; j < 8; ++j) { float x = (float)hv[j]; ssq += x * x; }
#pragma unroll
    for (int off = 32; off; off >>= 1) ssq += __shfl_xor(ssq, off);
    if (lane == 0) {
        float rtv = (float)(1.0 / sqrt((double)ssq + 1e-12));
        rt[k] = rtv;
        tnn[k] = ssq * rtv * rtv;
    }
    *(f16x8*)&tq[((size_t)lane * 128 + k) * 8] = hv;
}

// ---------------- k2: MFMA GEMM, hand-unrolled 2-deep feature prefetch + A prefetch ----------------
// tile: 128 k x 32 n, D chunked by 64, grid = B*64 = 2048 blocks
#define LOAD_A(c)                                                                              \
    do {                                                                                       \
        ap0 = *(const f16x8*)&tq[((size_t)((c) * 8 + 0 + hi) * 128 + w * 32 + l31) * 8];       \
        ap1 = *(const f16x8*)&tq[((size_t)((c) * 8 + 2 + hi) * 128 + w * 32 + l31) * 8];       \
        ap2 = *(const f16x8*)&tq[((size_t)((c) * 8 + 4 + hi) * 128 + w * 32 + l31) * 8];       \
        ap3 = *(const f16x8*)&tq[((size_t)((c) * 8 + 6 + hi) * 128 + w * 32 + l31) * 8];       \
    } while (0)

#define LOAD_F(d0, d1, c)                                                                      \
    do {                                                                                       \
        d0 = fbase[(size_t)r0 * 128 + (c) * 16 + fq];                                          \
        d1 = fbase[(size_t)r0 * 128 + (c) * 16 + fq + 8];                                      \
    } while (0)

#define WRITE_ONE(v, qq, buf)                                                                  \
    do {                                                                                       \
        f16x4 hv;                                                                              \
        hv[0] = (_Float16)(v).x; hv[1] = (_Float16)(v).y;                                      \
        hv[2] = (_Float16)(v).z; hv[3] = (_Float16)(v).w;                                      \
        float q0 = (float)hv[0], q1 = (float)hv[1], q2 = (float)hv[2], q3 = (float)hv[3];      \
        ss += q0 * q0 + q1 * q1 + q2 * q2 + q3 * q3;                                           \
        int sl = (qq) >> 1;                                                                    \
        int hh = (qq) & 1;                                                                     \
        *(f16x4*)&Bf[buf][r0 * 64 + ((sl ^ (r0 & 7)) << 3) + hh * 4] = hv;                     \
    } while (0)

#define WRITE_F(s0, s1, buf)                                                                   \
    do { WRITE_ONE(s0, fq, buf); WRITE_ONE(s1, fq + 8, buf); } while (0)

#define COMPUTE(buf)                                                                           \
    do {                                                                                       \
        f16x8 bf0 = *(const f16x8*)&Bf[buf][l31 * 64 + (((0 + hi) ^ (l31 & 7)) << 3)];         \
        acc = __builtin_amdgcn_mfma_f32_32x32x16_f16(ap0, bf0, acc, 0, 0, 0);                  \
        f16x8 bf1 = *(const f16x8*)&Bf[buf][l31 * 64 + (((2 + hi) ^ (l31 & 7)) << 3)];         \
        acc = __builtin_amdgcn_mfma_f32_32x32x16_f16(ap1, bf1, acc, 0, 0, 0);                  \
        f16x8 bf2 = *(const f16x8*)&Bf[buf][l31 * 64 + (((4 + hi) ^ (l31 & 7)) << 3)];         \
        acc = __builtin_amdgcn_mfma_f32_32x32x16_f16(ap2, bf2, acc, 0, 0, 0);                  \
        f16x8 bf3 = *(const f16x8*)&Bf[buf][l31 * 64 + (((6 + hi) ^ (l31 & 7)) << 3)];         \
        acc = __builtin_amdgcn_mfma_f32_32x32x16_f16(ap3, bf3, acc, 0, 0, 0);                  \
    } while (0)

__global__ __launch_bounds__(256, 4) void k_gemm(
    const float* __restrict__ features,  // [B][N][D] f32
    const _Float16* __restrict__ tq,     // frag-contiguous f16
    const float* __restrict__ rt, const float* __restrict__ tnn,
    _Float16* __restrict__ E,            // [B][K][N] f16, SHIFTED by exp(+18)
    float* __restrict__ A1)              // [B][N], shifted colsums
{
    __shared__ _Float16 Bf[2][32 * 64];  // 8 KB double-buffered f tile
    __shared__ float rowssq[32];
    __shared__ float csum[4][32];
    __shared__ float ldsrt[128], ldstnn[128];

    const int tid = threadIdx.x;
    const int b = blockIdx.x >> 6;
    const int n0 = (blockIdx.x & 63) * 32;
    const int w = tid >> 6;       // wave id: k rows [w*32, w*32+32)
    const int l = tid & 63;
    const int hi = l >> 5;
    const int l31 = l & 31;

    if (tid < 128) { ldsrt[tid] = rt[tid]; ldstnn[tid] = tnn[tid]; }

    const int fq = tid & 7;       // float4 sub-position within row chunk
    const int r0 = tid >> 3;      // 0..31 : feature row staged by this thread
    const float4* fbase = (const float4*)(features + ((size_t)(b * N_ + n0)) * D_);

    float ss = 0.f;               // f16-rounded partial sumsq of feature row r0
    f32x16 acc;
#pragma unroll
    for (int i = 0; i < 16; ++i) acc[i] = 0.f;

    float4 brA0, brA1, brB0, brB1;   // 2-deep prefetch, named scalars
    f16x8 ap0, ap1, ap2, ap3;        // A fragments for current chunk

    // prologue: chunk0 -> brA -> Bf[0]; chunk1 -> brB in flight; A frags chunk0
    LOAD_F(brA0, brA1, 0);
    LOAD_F(brB0, brB1, 1);
    LOAD_A(0);
    WRITE_F(brA0, brA1, 0);
    __syncthreads();

    // c=0
    LOAD_F(brA0, brA1, 2); COMPUTE(0); LOAD_A(1); WRITE_F(brB0, brB1, 1); __syncthreads();
    // c=1
    LOAD_F(brB0, brB1, 3); COMPUTE(1); LOAD_A(2); WRITE_F(brA0, brA1, 0); __syncthreads();
    // c=2
    LOAD_F(brA0, brA1, 4); COMPUTE(0); LOAD_A(3); WRITE_F(brB0, brB1, 1); __syncthreads();
    // c=3
    LOAD_F(brB0, brB1, 5); COMPUTE(1); LOAD_A(4); WRITE_F(brA0, brA1, 0); __syncthreads();
    // c=4
    LOAD_F(brA0, brA1, 6); COMPUTE(0); LOAD_A(5); WRITE_F(brB0, brB1, 1); __syncthreads();
    // c=5
    LOAD_F(brB0, brB1, 7); COMPUTE(1); LOAD_A(6); WRITE_F(brA0, brA1, 0); __syncthreads();
    // c=6
    COMPUTE(0); LOAD_A(7); WRITE_F(brB0, brB1, 1); __syncthreads();
    // c=7
    COMPUTE(1);

    // ---- epilogue ----
    ss += __shfl_xor(ss, 1);
    ss += __shfl_xor(ss, 2);
    ss += __shfl_xor(ss, 4);
    if (fq == 0) rowssq[r0] = ss;
    __syncthreads();

    const int n = n0 + l31;
    float rsq = rowssq[l31];
    float rf = (float)(1.0 / sqrt((double)rsq + 1e-12));
    float fnn = rsq * rf * rf;
    float cs = 0.f;
#pragma unroll
    for (int r = 0; r < 16; ++r) {
        int krow = (r & 3) + 8 * (r >> 2) + 4 * hi;
        int k = w * 32 + krow;
        float cb = ldstnn[k] + fnn - 2.0f * ldsrt[k] * rf * acc[r];
        float e = expf(SHIFT_ - GAMMA_ * cb);   // shifted into f16 normal range
        _Float16 eh = (_Float16)e;
        cs += (float)eh;                        // sum exactly what we store
        E[((size_t)(b * K_ + k)) * N_ + n] = eh;
    }
    cs += __shfl_xor(cs, 32);                   // merge hi-half's k rows
    if (!hi) csum[w][l31] = cs;
    __syncthreads();
    if (tid < 32)
        A1[b * N_ + n0 + tid] = csum[0][tid] + csum[1][tid] + csum[2][tid] + csum[3][tid];
}

// ---------------- k4: collapsed Sinkhorn loop (R13 exact) ----------------
__global__ __launch_bounds__(256) void k_sinkhorn(const float* __restrict__ tr,
                                                  const float* __restrict__ c_u,
                                                  const float* __restrict__ A1,
                                                  float* __restrict__ out,
                                                  float* __restrict__ wfb) {
    __shared__ float sc0[4], sc1[4], sres[2];
    int b = blockIdx.x, tid = threadIdx.x;
    float mu = tr[b];
    const float nf = (float)N_;
    float a0[8], a1[8], w[8];
#pragma unroll
    for (int r = 0; r < 8; ++r) {
        int n = tid + 256 * r;
        a0[r] = expf(-GAMMA_ * c_u[b * N_ + n]);
        a1[r] = A1[b * N_ + n] * EXP_NEG_SHIFT_;   // undo global shift exactly in f32
        w[r] = 1.f;
    }
    float alpha = 1.f, beta = 1.f;
    for (int s = 0; s < STEPS_; ++s) {
        float p0 = 0.f, p1 = 0.f;
#pragma unroll
        for (int r = 0; r < 8; ++r) {
            float cs = w[r] * (alpha * a0[r] + beta * a1[r]);
            w[r] = w[r] / (cs * nf + EPS_);
            p0 += a0[r] * w[r];
            p1 += a1[r] * w[r];
        }
#pragma unroll
        for (int off = 32; off; off >>= 1) {
            p0 += __shfl_xor(p0, off);
            p1 += __shfl_xor(p1, off);
        }
        int wid = tid >> 6;
        if ((tid & 63) == 0) { sc0[wid] = p0; sc1[wid] = p1; }
        __syncthreads();
        if (tid == 0) {
            sres[0] = sc0[0] + sc0[1] + sc0[2] + sc0[3];
            sres[1] = sc1[0] + sc1[1] + sc1[2] + sc1[3];
        }
        __syncthreads();
        float s0 = alpha * sres[0], ssum = beta * sres[1];
        alpha *= (1.f - mu) / (s0 + EPS_);
        beta *= mu / (ssum + EPS_);
    }
#pragma unroll
    for (int r = 0; r < 8; ++r) {
        int n = tid + 256 * r;
        float cs = w[r] * (alpha * a0[r] + beta * a1[r]);
        float wf = w[r] / (cs * nf + EPS_);
        out[(size_t)b * (K_ + 1) * N_ + n] = alpha * a0[r] * wf;  // row 0
        wfb[b * N_ + n] = beta * wf * EXP_NEG_SHIFT_;             // fold shift for rows 1..K
    }
}

// ---------------- k5: P rows 1..K = E * wfb (R13 exact) ----------------
__global__ void k_scale(const _Float16* __restrict__ E, const float* __restrict__ wfb,
                        float* __restrict__ out) {
    size_t g = (size_t)blockIdx.x * 256 + threadIdx.x;
    size_t idx = g * 8;
    int b = (int)(idx >> 18);            // / (K*N) = 2^18
    int rem = (int)(idx & ((K_ * N_) - 1));
    int k = rem >> 11, n = rem & (N_ - 1);
    f16x8 e = *(const f16x8*)&E[idx];
    float4 w0 = *(const float4*)&wfb[b * N_ + n];
    float4 w1 = *(const float4*)&wfb[b * N_ + n + 4];
    float* op = &out[((size_t)(b * (K_ + 1) + 1 + k)) * N_ + n];
    float4 o0, o1;
    o0.x = (float)e[0] * w0.x; o0.y = (float)e[1] * w0.y;
    o0.z = (float)e[2] * w0.z; o0.w = (float)e[3] * w0.w;
    o1.x = (float)e[4] * w1.x; o1.y = (float)e[5] * w1.y;
    o1.z = (float)e[6] * w1.z; o1.w = (float)e[7] * w1.w;
    *(float4*)op = o0;
    *(float4*)(op + 4) = o1;
}

extern "C" void kernel_launch(void* const* d_in, const int* in_sizes, int n_in,
                              void* d_out, int out_size, void* d_ws, size_t ws_size,
                              hipStream_t stream) {
    const float* features = (const float*)d_in[0];
    const float* tr = (const float*)d_in[1];
    const float* c_u = (const float*)d_in[2];
    const float* ts = (const float*)d_in[3];
    float* out = (float*)d_out;

    char* ws = (char*)d_ws;
    _Float16* tq = (_Float16*)ws;                 // 128*512 f16 = 128 KiB
    float* rt = (float*)(ws + 131072);            // 512 B
    float* tnn = (float*)(ws + 131584);           // 512 B
    float* A1 = (float*)(ws + 132096);            // B*N f32 = 256 KiB
    float* wfb = (float*)(ws + 132096 + 262144);  // 256 KiB
    _Float16* E = (_Float16*)(ws + 132096 + 524288);  // B*K*N f16 = 16 MiB
    (void)in_sizes; (void)n_in; (void)out_size; (void)ws_size;

    k_prep_t<<<K_, 64, 0, stream>>>(ts, tq, rt, tnn);
    k_gemm<<<B_ * 64, 256, 0, stream>>>(features, tq, rt, tnn, E, A1);
    k_sinkhorn<<<B_, 256, 0, stream>>>(tr, c_u, A1, out, wfb);
    k_scale<<<(B_ * K_ * N_) / (8 * 256), 256, 0, stream>>>(E, wfb, out);
}